// Round 1
// baseline (247.501 us; speedup 1.0000x reference)
//
#include <hip/hip_runtime.h>

// RoIPool3d: B=2, P=8192, R=64, C=64, OUT=5, NVOX=125
// out[(b*R+r)*C*NVOX + c*NVOX + (vx*5+vy)*5+vz] = max over inside points, 0 if empty.

constexpr int OUTD = 5;
constexpr int NVOX = OUTD * OUTD * OUTD;   // 125
constexpr int Bn = 2;
constexpr int Pn = 8192;
constexpr int Rn = 64;
constexpr int Cn = 64;

// Order-preserving map float -> unsigned, so atomicMax(unsigned) == float max.
__device__ __forceinline__ unsigned fmap(float x) {
    unsigned u = __float_as_uint(x);
    return (u & 0x80000000u) ? ~u : (u | 0x80000000u);
}
__device__ __forceinline__ float funmap(unsigned u) {
    return (u & 0x80000000u) ? __uint_as_float(u & 0x7fffffffu)
                             : __uint_as_float(~u);
}

__global__ __launch_bounds__(256)
void roipool3d_kernel(const float* __restrict__ pts,   // [B,P,3]
                      const float* __restrict__ feat,  // [B,C,P]
                      const float* __restrict__ rois,  // [B,R,7]
                      float* __restrict__ out)         // [B*R,C,NVOX]
{
    const int br  = blockIdx.x;          // 0..B*R-1, roi-major per batch
    const int b   = br / Rn;
    const int tid = threadIdx.x;

    __shared__ unsigned pool[Cn * NVOX]; // 32 KB, layout [c][v]
    __shared__ int occ[NVOX];

    for (int i = tid; i < Cn * NVOX; i += 256) pool[i] = 0u; // 0 < fmap(any finite/-inf)
    if (tid < NVOX) occ[tid] = 0;
    __syncthreads();

    // roi params (wave-uniform scalar loads); geometry in fp64 to keep our
    // boundary decisions "exact" relative to the fp32 reference's noise.
    const float* roi = rois + br * 7;
    const double cx = (double)roi[0];
    const double cy = (double)roi[1];
    const double dx = (double)roi[3];
    const double dy = (double)roi[4];
    const double dz = (double)roi[5];
    const double cz = (double)roi[2] + 0.5 * dz;   // geometric z center
    const double ry = (double)roi[6];
    const double cs = cos(ry), sn = sin(ry);
    const double hx = 0.5 * dx, hy = 0.5 * dy, hz = 0.5 * dz;
    const double ivx = (double)OUTD / dx;          // 1/voxel_size
    const double ivy = (double)OUTD / dy;
    const double ivz = (double)OUTD / dz;

    const float* pb = pts  + (size_t)b * Pn * 3;
    const float* fb = feat + (size_t)b * Cn * Pn;

    for (int p = tid; p < Pn; p += 256) {
        const double sx = (double)pb[p * 3 + 0] - cx;
        const double sy = (double)pb[p * 3 + 1] - cy;
        const double sz = (double)pb[p * 3 + 2] - cz;
        // rotate world -> box frame (by -ry around z)
        const double lx =  sx * cs + sy * sn;
        const double ly = -sx * sn + sy * cs;
        const double lz = sz;
        if (fabs(lx) < hx && fabs(ly) < hy && fabs(lz) < hz) {
            int vx = (int)floor((lx + hx) * ivx);
            int vy = (int)floor((ly + hy) * ivy);
            int vz = (int)floor((lz + hz) * ivz);
            vx = min(max(vx, 0), OUTD - 1);
            vy = min(max(vy, 0), OUTD - 1);
            vz = min(max(vz, 0), OUTD - 1);
            const int vid = (vx * OUTD + vy) * OUTD + vz;
            occ[vid] = 1;                          // benign race (all write 1)
            #pragma unroll 8
            for (int c = 0; c < Cn; ++c) {
                atomicMax(&pool[c * NVOX + vid], fmap(fb[c * Pn + p]));
            }
        }
    }
    __syncthreads();

    // Epilogue: write the full roi chunk (also serves as zero-init for empties).
    float* ob = out + (size_t)br * Cn * NVOX;
    for (int i = tid; i < Cn * NVOX; i += 256) {
        const int c = i / NVOX;
        const int v = i - c * NVOX;
        ob[i] = occ[v] ? funmap(pool[i]) : 0.0f;
    }
}

extern "C" void kernel_launch(void* const* d_in, const int* in_sizes, int n_in,
                              void* d_out, int out_size, void* d_ws, size_t ws_size,
                              hipStream_t stream) {
    const float* pts  = (const float*)d_in[0];  // [B,P,3]
    const float* feat = (const float*)d_in[1];  // [B,C,P]
    const float* rois = (const float*)d_in[2];  // [B,R,7]
    float* out = (float*)d_out;                 // [B*R,C,NVOX] fp32

    roipool3d_kernel<<<Bn * Rn, 256, 0, stream>>>(pts, feat, rois, out);
}

// Round 2
// 92.903 us; speedup vs baseline: 2.6641x; 2.6641x over previous
//
#include <hip/hip_runtime.h>

// RoIPool3d: B=2, P=8192, R=64, C=64, OUT=5, NVOX=125
// out[(b*R+r)*C*NVOX + c*NVOX + (vx*5+vy)*5+vz] = max over inside points, 0 if empty.
//
// Strategy (R2): R1 was parallelism-starved (128 blocks, VALUBusy 0.9%).
// Use d_out itself as a global uint-mapped atomicMax accumulator so the
// geometry/scatter phase can run with 4096 blocks (1 point/thread/roi).

constexpr int OUTD = 5;
constexpr int NVOX = OUTD * OUTD * OUTD;     // 125
constexpr int Bn = 2;
constexpr int Pn = 8192;
constexpr int Rn = 64;
constexpr int Cn = 64;
constexpr int BR = Bn * Rn;                  // 128
constexpr int OUT_ELEMS = BR * Cn * NVOX;    // 1,024,000
constexpr int OCC_ELEMS = BR * NVOX;         // 16,000
constexpr int NPAR = 12;                     // doubles per roi (11 used, pad)

// ws layout: [0 .. BR*NPAR*8) roi params (doubles); occ ints at byte 16384.
constexpr size_t WS_OCC_OFF = 16384;

// Order-preserving map float -> unsigned: atomicMax(unsigned) == float max.
__device__ __forceinline__ unsigned fmap(float x) {
    unsigned u = __float_as_uint(x);
    return (u & 0x80000000u) ? ~u : (u | 0x80000000u);
}
__device__ __forceinline__ float funmap(unsigned u) {
    return (u & 0x80000000u) ? __uint_as_float(u & 0x7fffffffu)
                             : __uint_as_float(~u);
}

// Zero the accumulator (mapped-domain min is 0u) + occ flags; threads <BR also
// precompute per-roi fp64 geometry params so scatter blocks just load them.
__global__ __launch_bounds__(256)
void setup_kernel(const float* __restrict__ rois, unsigned* out_u,
                  double* __restrict__ par, int* __restrict__ occ) {
    const int gid = blockIdx.x * 256 + threadIdx.x;
    const int stride = gridDim.x * 256;
    for (int i = gid; i < OUT_ELEMS; i += stride) out_u[i] = 0u;
    for (int i = gid; i < OCC_ELEMS; i += stride) occ[i] = 0;
    if (gid < BR) {
        const float* r = rois + gid * 7;
        const double dx = (double)r[3], dy = (double)r[4], dz = (double)r[5];
        const double ry = (double)r[6];
        double* p = par + gid * NPAR;
        p[0] = (double)r[0];                  // cx
        p[1] = (double)r[1];                  // cy
        p[2] = (double)r[2] + 0.5 * dz;       // cz (geometric center)
        p[3] = cos(ry);
        p[4] = sin(ry);
        p[5] = 0.5 * dx;                      // hx
        p[6] = 0.5 * dy;                      // hy
        p[7] = 0.5 * dz;                      // hz
        p[8] = (double)OUTD / dx;             // 1/voxel size
        p[9] = (double)OUTD / dy;
        p[10] = (double)OUTD / dz;
    }
}

// grid = (Pn/256, BR): one point per thread per roi.
__global__ __launch_bounds__(256)
void scatter_kernel(const float* __restrict__ pts,   // [B,P,3]
                    const float* __restrict__ feat,  // [B,C,P]
                    const double* __restrict__ par,
                    unsigned* out_u, int* __restrict__ occ) {
    const int br = blockIdx.y;
    const int b  = br >> 6;                   // br / Rn
    const int p  = blockIdx.x * 256 + threadIdx.x;

    const double* q = par + br * NPAR;        // wave-uniform loads
    const double cx = q[0], cy = q[1], cz = q[2];
    const double cs = q[3], sn = q[4];
    const double hx = q[5], hy = q[6], hz = q[7];
    const double ivx = q[8], ivy = q[9], ivz = q[10];

    const float* pb = pts + ((size_t)b * Pn + p) * 3;
    const double sx = (double)pb[0] - cx;
    const double sy = (double)pb[1] - cy;
    const double sz = (double)pb[2] - cz;
    const double lx =  sx * cs + sy * sn;     // rotate world -> box (-ry)
    const double ly = -sx * sn + sy * cs;
    const double lz = sz;

    if (fabs(lx) < hx && fabs(ly) < hy && fabs(lz) < hz) {
        int vx = (int)floor((lx + hx) * ivx);
        int vy = (int)floor((ly + hy) * ivy);
        int vz = (int)floor((lz + hz) * ivz);
        vx = min(max(vx, 0), OUTD - 1);
        vy = min(max(vy, 0), OUTD - 1);
        vz = min(max(vz, 0), OUTD - 1);
        const int vid = (vx * OUTD + vy) * OUTD + vz;
        occ[br * NVOX + vid] = 1;             // benign race (all write 1)
        const float* fb = feat + (size_t)b * Cn * Pn + p;
        unsigned* ob = out_u + (size_t)br * Cn * NVOX + vid;
        #pragma unroll 8
        for (int c = 0; c < Cn; ++c) {
            atomicMax(ob + c * NVOX, fmap(fb[(size_t)c * Pn]));
        }
    }
}

// In-place: uint-mapped accumulator -> float, empty voxels -> 0.
__global__ __launch_bounds__(256)
void finalize_kernel(unsigned* out_u, const int* __restrict__ occ) {
    const int gid = blockIdx.x * 256 + threadIdx.x;
    const int stride = gridDim.x * 256;
    for (int i = gid; i < OUT_ELEMS; i += stride) {
        const unsigned u = out_u[i];
        const int v  = i % NVOX;
        const int br = i / (Cn * NVOX);
        const float val = occ[br * NVOX + v] ? funmap(u) : 0.0f;
        ((float*)out_u)[i] = val;             // one thread per element: safe
    }
}

extern "C" void kernel_launch(void* const* d_in, const int* in_sizes, int n_in,
                              void* d_out, int out_size, void* d_ws, size_t ws_size,
                              hipStream_t stream) {
    const float* pts  = (const float*)d_in[0];  // [B,P,3]
    const float* feat = (const float*)d_in[1];  // [B,C,P]
    const float* rois = (const float*)d_in[2];  // [B,R,7]
    unsigned* out_u = (unsigned*)d_out;
    double* par = (double*)d_ws;
    int* occ = (int*)((char*)d_ws + WS_OCC_OFF);

    setup_kernel<<<256, 256, 0, stream>>>(rois, out_u, par, occ);
    scatter_kernel<<<dim3(Pn / 256, BR), 256, 0, stream>>>(pts, feat, par, out_u, occ);
    finalize_kernel<<<512, 256, 0, stream>>>(out_u, occ);
}

// Round 3
// 67.860 us; speedup vs baseline: 3.6473x; 1.3690x over previous
//
#include <hip/hip_runtime.h>

// RoIPool3d: B=2, P=8192, R=64, C=64, OUT=5, NVOX=125
// out[(b*R+r)*C*NVOX + c*NVOX + (vx*5+vy)*5+vz] = max over inside points, 0 if empty.
//
// R3: single-dispatch version. R2 showed total time dominated by harness
// fills/restores (~50 us fixed) plus our 3 dispatches; fold everything into
// one kernel with LDS-private accumulation (no d_out zero-init needed: the
// epilogue writes every element of the roi chunk).
//
// R1's LDS version was slow because ~1 lane did 64 serial scattered feature
// loads per inside point. Here phase A builds an LDS worklist of inside
// points; phase B uses one wave per entry, one lane per channel: the 64-ch
// gather is a single vector load, and pool[c*125+vid] strides 29 mod 32
// banks -> 2-way aliasing only (free).

constexpr int OUTD = 5;
constexpr int NVOX = OUTD * OUTD * OUTD;   // 125
constexpr int Bn = 2;
constexpr int Pn = 8192;
constexpr int Rn = 64;
constexpr int Cn = 64;
constexpr int BR = Bn * Rn;                // 128
constexpr int NT = 1024;                   // threads per block

// Order-preserving map float -> unsigned: atomicMax(unsigned) == float max.
__device__ __forceinline__ unsigned fmap(float x) {
    unsigned u = __float_as_uint(x);
    return (u & 0x80000000u) ? ~u : (u | 0x80000000u);
}
__device__ __forceinline__ float funmap(unsigned u) {
    return (u & 0x80000000u) ? __uint_as_float(u & 0x7fffffffu)
                             : __uint_as_float(~u);
}

__global__ __launch_bounds__(NT)
void roipool3d_kernel(const float* __restrict__ pts,   // [B,P,3]
                      const float* __restrict__ feat,  // [B,C,P]
                      const float* __restrict__ rois,  // [B,R,7]
                      float* __restrict__ out)         // [B*R,C,NVOX]
{
    const int br  = blockIdx.x;            // one block per (b, roi)
    const int b   = br >> 6;               // br / Rn
    const int tid = threadIdx.x;

    __shared__ unsigned pool[Cn * NVOX];   // 32000 B, layout [c][v]
    __shared__ unsigned list[Pn];          // 32768 B worklist: (p<<7)|vid
    __shared__ int occ[NVOX];
    __shared__ int cnt;
    __shared__ double par[11];

    for (int i = tid; i < Cn * NVOX; i += NT) pool[i] = 0u; // 0 == fmap min
    if (tid < NVOX) occ[tid] = 0;
    if (tid == 0) {
        cnt = 0;
        const float* r = rois + br * 7;
        const double dx = (double)r[3], dy = (double)r[4], dz = (double)r[5];
        const double ry = (double)r[6];
        par[0] = (double)r[0];             // cx
        par[1] = (double)r[1];             // cy
        par[2] = (double)r[2] + 0.5 * dz;  // cz (geometric center)
        par[3] = cos(ry);
        par[4] = sin(ry);
        par[5] = 0.5 * dx;                 // hx
        par[6] = 0.5 * dy;                 // hy
        par[7] = 0.5 * dz;                 // hz
        par[8] = (double)OUTD / dx;        // inverse voxel size
        par[9] = (double)OUTD / dy;
        par[10] = (double)OUTD / dz;
    }
    __syncthreads();

    const double cx = par[0], cy = par[1], cz = par[2];
    const double cs = par[3], sn = par[4];
    const double hx = par[5], hy = par[6], hz = par[7];
    const double ivx = par[8], ivy = par[9], ivz = par[10];

    // Phase A: test points, append inside ones to the worklist.
    const float* pb = pts + (size_t)b * Pn * 3;
    #pragma unroll
    for (int it = 0; it < Pn / NT; ++it) {
        const int p = it * NT + tid;
        const double sx = (double)pb[p * 3 + 0] - cx;
        const double sy = (double)pb[p * 3 + 1] - cy;
        const double sz = (double)pb[p * 3 + 2] - cz;
        const double lx =  sx * cs + sy * sn;  // rotate world -> box (-ry)
        const double ly = -sx * sn + sy * cs;
        const double lz = sz;
        if (fabs(lx) < hx && fabs(ly) < hy && fabs(lz) < hz) {
            int vx = (int)floor((lx + hx) * ivx);
            int vy = (int)floor((ly + hy) * ivy);
            int vz = (int)floor((lz + hz) * ivz);
            vx = min(max(vx, 0), OUTD - 1);
            vy = min(max(vy, 0), OUTD - 1);
            vz = min(max(vz, 0), OUTD - 1);
            const int vid = (vx * OUTD + vy) * OUTD + vz;
            occ[vid] = 1;                       // benign race
            const int idx = atomicAdd(&cnt, 1);
            list[idx] = ((unsigned)p << 7) | (unsigned)vid;
        }
    }
    __syncthreads();

    // Phase B: one wave per entry, one lane per channel.
    const int n = cnt;
    const int wave = tid >> 6;                  // 0..15
    const int c    = tid & 63;                  // channel
    const float* fb = feat + (size_t)b * Cn * Pn + (size_t)c * Pn;
    for (int i = wave; i < n; i += NT / 64) {
        const unsigned e = list[i];
        const int p   = (int)(e >> 7);
        const int vid = (int)(e & 127u);
        atomicMax(&pool[c * NVOX + vid], fmap(fb[p]));
    }
    __syncthreads();

    // Epilogue: write full roi chunk (covers empty voxels -> 0).
    float* ob = out + (size_t)br * Cn * NVOX;
    #pragma unroll
    for (int it = 0; it < (Cn * NVOX + NT - 1) / NT; ++it) {
        const int i = it * NT + tid;
        if (i < Cn * NVOX) {
            const int v = i % NVOX;
            ob[i] = occ[v] ? funmap(pool[i]) : 0.0f;
        }
    }
}

extern "C" void kernel_launch(void* const* d_in, const int* in_sizes, int n_in,
                              void* d_out, int out_size, void* d_ws, size_t ws_size,
                              hipStream_t stream) {
    const float* pts  = (const float*)d_in[0];  // [B,P,3]
    const float* feat = (const float*)d_in[1];  // [B,C,P]
    const float* rois = (const float*)d_in[2];  // [B,R,7]
    float* out = (float*)d_out;

    roipool3d_kernel<<<BR, NT, 0, stream>>>(pts, feat, rois, out);
}